// Round 1
// baseline (530.790 us; speedup 1.0000x reference)
//
#include <hip/hip_runtime.h>
#include <math.h>

// Problem constants (B,T,J,D) = (64, 2048, 128, 512)
#define BB 64
#define TT 2048
#define JJ 128
#define DD 512

// ---------------- Kernel A: S[b][j][t] = sum_d Q[b][j][d]*w[d]*C[b][t][d] ----
// 64(j) x 64(t) tile, K-chunk 32, 256 threads each computing 4x4.
// LDS stored transposed [k][row] with row length padded to 68 (16B-aligned
// float4 rows, conflict-free b128 fragment reads).
#define TILE 64
#define TK 32
#define LROW 68

__global__ __launch_bounds__(256)
void sim_gemm_kernel(const float* __restrict__ Qm, const float* __restrict__ Cm,
                     const float* __restrict__ w, float* __restrict__ S) {
  const int ttile = blockIdx.x;   // 0..31
  const int jtile = blockIdx.y;   // 0..1
  const int b     = blockIdx.z;   // 0..63
  const int tid = threadIdx.x;
  const int tx = tid & 15;        // t-dir
  const int ty = tid >> 4;        // j-dir

  __shared__ float Ql[TK][LROW];  // [k][j]
  __shared__ float Cl[TK][LROW];  // [k][t]

  const int j0 = jtile * TILE;
  const int t0 = ttile * TILE;

  const float* Qb = Qm + ((size_t)b * JJ + j0) * DD;
  const float* Cb = Cm + ((size_t)b * TT + t0) * DD;

  float acc[4][4];
#pragma unroll
  for (int i = 0; i < 4; i++)
#pragma unroll
    for (int l = 0; l < 4; l++) acc[i][l] = 0.f;

  const int row_half = tid >> 3;        // 0..31
  const int c4 = (tid & 7) * 4;         // d offset within chunk

  for (int d0 = 0; d0 < DD; d0 += TK) {
    __syncthreads();
    const float4 wv = *(const float4*)(w + d0 + c4);
#pragma unroll
    for (int h = 0; h < 2; h++) {
      const int row = row_half + h * 32;
      const float4 qv = *(const float4*)(Qb + (size_t)row * DD + d0 + c4);
      Ql[c4 + 0][row] = qv.x * wv.x;
      Ql[c4 + 1][row] = qv.y * wv.y;
      Ql[c4 + 2][row] = qv.z * wv.z;
      Ql[c4 + 3][row] = qv.w * wv.w;
      const float4 cv = *(const float4*)(Cb + (size_t)row * DD + d0 + c4);
      Cl[c4 + 0][row] = cv.x;
      Cl[c4 + 1][row] = cv.y;
      Cl[c4 + 2][row] = cv.z;
      Cl[c4 + 3][row] = cv.w;
    }
    __syncthreads();
#pragma unroll
    for (int k = 0; k < TK; k++) {
      const float4 av = *(const float4*)&Ql[k][ty * 4];
      const float4 bv = *(const float4*)&Cl[k][tx * 4];
      const float a0 = av.x, a1 = av.y, a2 = av.z, a3 = av.w;
      const float b0 = bv.x, b1 = bv.y, b2 = bv.z, b3 = bv.w;
      acc[0][0] += a0 * b0; acc[0][1] += a0 * b1; acc[0][2] += a0 * b2; acc[0][3] += a0 * b3;
      acc[1][0] += a1 * b0; acc[1][1] += a1 * b1; acc[1][2] += a1 * b2; acc[1][3] += a1 * b3;
      acc[2][0] += a2 * b0; acc[2][1] += a2 * b1; acc[2][2] += a2 * b2; acc[2][3] += a2 * b3;
      acc[3][0] += a3 * b0; acc[3][1] += a3 * b1; acc[3][2] += a3 * b2; acc[3][3] += a3 * b3;
    }
  }

  // store: S[b][j0+ty*4+i][t0+tx*4 .. +3]
#pragma unroll
  for (int i = 0; i < 4; i++) {
    float4 v;
    v.x = acc[i][0]; v.y = acc[i][1]; v.z = acc[i][2]; v.w = acc[i][3];
    *(float4*)(S + ((size_t)b * JJ + j0 + ty * 4 + i) * TT + t0 + tx * 4) = v;
  }
}

// ---------------- Kernel B: per-(b,j) softmax stats over valid t -------------
__global__ __launch_bounds__(256)
void softmax_stats_kernel(const float* __restrict__ S, const int* __restrict__ qlen,
                          const int* __restrict__ clen, float* __restrict__ m_out,
                          float* __restrict__ r_out) {
  const int j = blockIdx.x;
  const int b = blockIdx.y;
  if (j >= qlen[b]) return;  // masked-out question positions never contribute
  const int cl = clen[b];
  const float* row = S + ((size_t)b * JJ + j) * TT;
  const int tid = threadIdx.x;

  __shared__ float redm[4];
  __shared__ float reds[4];

  float m = -INFINITY;
  for (int t = tid; t < cl; t += 256) m = fmaxf(m, row[t]);
#pragma unroll
  for (int off = 32; off > 0; off >>= 1) m = fmaxf(m, __shfl_down(m, off, 64));
  if ((tid & 63) == 0) redm[tid >> 6] = m;
  __syncthreads();
  m = fmaxf(fmaxf(redm[0], redm[1]), fmaxf(redm[2], redm[3]));

  float s = 0.f;
  for (int t = tid; t < cl; t += 256) s += __expf(row[t] - m);
#pragma unroll
  for (int off = 32; off > 0; off >>= 1) s += __shfl_down(s, off, 64);
  if ((tid & 63) == 0) reds[tid >> 6] = s;
  __syncthreads();
  s = reds[0] + reds[1] + reds[2] + reds[3];

  if (tid == 0) {
    m_out[(size_t)b * JJ + j] = m;
    r_out[(size_t)b * JJ + j] = 1.f / s;
  }
}

// ---------------- Kernel C: out[b,t] = sum_{j<qlen} exp(S-m)*r ---------------
__global__ __launch_bounds__(256)
void out_kernel(const float* __restrict__ S, const float* __restrict__ m_arr,
                const float* __restrict__ r_arr, const int* __restrict__ qlen,
                const int* __restrict__ clen, float* __restrict__ out) {
  const int b = blockIdx.y;
  const int t = blockIdx.x * 256 + threadIdx.x;
  const int ql = qlen[b];
  const int cl = clen[b];

  __shared__ float lm[JJ];
  __shared__ float lr[JJ];
  if (threadIdx.x < ql) {
    lm[threadIdx.x] = m_arr[(size_t)b * JJ + threadIdx.x];
    lr[threadIdx.x] = r_arr[(size_t)b * JJ + threadIdx.x];
  }
  __syncthreads();

  float acc = 0.f;
  if (t < cl) {
    const float* col = S + (size_t)b * JJ * TT + t;
    for (int j = 0; j < ql; j++) {
      acc += __expf(col[(size_t)j * TT] - lm[j]) * lr[j];
    }
  }
  out[(size_t)b * TT + t] = acc;
}

extern "C" void kernel_launch(void* const* d_in, const int* in_sizes, int n_in,
                              void* d_out, int out_size, void* d_ws, size_t ws_size,
                              hipStream_t stream) {
  const float* question = (const float*)d_in[0];  // (B,J,D)
  const float* context  = (const float*)d_in[1];  // (B,T,D)
  const int*   qlen     = (const int*)d_in[2];    // (B,)
  const int*   clen     = (const int*)d_in[3];    // (B,)
  const float* weight   = (const float*)d_in[4];  // (D,1)
  float* out = (float*)d_out;                     // (B,T,1) f32

  // Workspace: S (B*J*T f32 = 64 MB) + m (B*J) + r (B*J)
  float* S = (float*)d_ws;
  float* m_arr = S + (size_t)BB * JJ * TT;
  float* r_arr = m_arr + (size_t)BB * JJ;

  sim_gemm_kernel<<<dim3(TT / TILE, JJ / TILE, BB), 256, 0, stream>>>(
      question, context, weight, S);
  softmax_stats_kernel<<<dim3(JJ, BB), 256, 0, stream>>>(S, qlen, clen, m_arr, r_arr);
  out_kernel<<<dim3(TT / 256, BB), 256, 0, stream>>>(S, m_arr, r_arr, qlen, clen, out);
}

// Round 2
// 445.691 us; speedup vs baseline: 1.1909x; 1.1909x over previous
//
#include <hip/hip_runtime.h>
#include <math.h>

// Problem constants (B,T,J,D) = (64, 2048, 128, 512)
#define BB 64
#define TT 2048
#define JJ 128
#define DD 512
#define BK 32    // K chunk per step (one 16x16x32 MFMA K)

typedef short short8 __attribute__((ext_vector_type(8)));
typedef float f32x4 __attribute__((ext_vector_type(4)));

__device__ inline unsigned pk_hi(float a, float b) {
  // (hi16(a)) | (hi16(b) << 16) -- bf16 truncation pack of 2 fp32
  return __builtin_amdgcn_perm(__float_as_uint(b), __float_as_uint(a), 0x07060302u);
}
__device__ inline float truncbf(float x) {
  return __uint_as_float(__float_as_uint(x) & 0xFFFF0000u);
}
// 8 fp32 (two float4) -> hi chunk (8 bf16) + lo chunk (8 bf16)
__device__ inline void pack8(float4 a, float4 b, uint4& h, uint4& l) {
  h = make_uint4(pk_hi(a.x, a.y), pk_hi(a.z, a.w), pk_hi(b.x, b.y), pk_hi(b.z, b.w));
  float l0 = a.x - truncbf(a.x), l1 = a.y - truncbf(a.y);
  float l2 = a.z - truncbf(a.z), l3 = a.w - truncbf(a.w);
  float l4 = b.x - truncbf(b.x), l5 = b.y - truncbf(b.y);
  float l6 = b.z - truncbf(b.z), l7 = b.w - truncbf(b.w);
  l = make_uint4(pk_hi(l0, l1), pk_hi(l2, l3), pk_hi(l4, l5), pk_hi(l6, l7));
}
__device__ inline short8 bc8(uint4 u) { return __builtin_bit_cast(short8, u); }

// ---------------- Kernel A: S[b][j][t] = sum_d Q[b][j][d]*w[d]*C[b][t][d] ----
// 128x128 tile, split-bf16 (hi/lo) 3-MFMA scheme, 16 K-steps of 32.
// LDS tiles [row][4 chunks of 8 bf16], chunk XOR-swizzled by (row>>1)&3.
__global__ __launch_bounds__(256, 3)
void sim_gemm_mfma(const float* __restrict__ Qm, const float* __restrict__ Cm,
                   const float* __restrict__ w, float* __restrict__ S) {
  __shared__ uint4 Ahi[128 * 4];
  __shared__ uint4 Alo[128 * 4];
  __shared__ uint4 Bhi[128 * 4];
  __shared__ uint4 Blo[128 * 4];

  const int tid = threadIdx.x;
  const int b = blockIdx.y;
  const int t0 = blockIdx.x * 128;

  // ---- staging assignment: thread -> row sr (0..127), chunk pair (sc0, sc0+1)
  const int sr = tid >> 1;
  const int sc0 = (tid & 1) * 2;
  const int ssw = (sr >> 1) & 3;
  const int slotA0 = sr * 4 + (sc0 ^ ssw);
  const int slotA1 = sr * 4 + ((sc0 + 1) ^ ssw);

  const float* qp = Qm + ((size_t)b * JJ + sr) * DD + sc0 * 8;
  const float* cp = Cm + ((size_t)b * TT + t0 + sr) * DD + sc0 * 8;
  const float* wp = w + sc0 * 8;

  // ---- MFMA fragment assignment: 4 waves in 2x2 over 128x128
  const int lane = tid & 63;
  const int wv = tid >> 6;
  const int wm = (wv & 1) * 64;
  const int wn = (wv >> 1) * 64;
  const int l15 = lane & 15;
  const int q = lane >> 4;
  const int fchunk = q ^ ((l15 >> 1) & 3);

  int aslot[4], bslot[4];
#pragma unroll
  for (int i = 0; i < 4; i++) {
    aslot[i] = (wm + i * 16 + l15) * 4 + fchunk;
    bslot[i] = (wn + i * 16 + l15) * 4 + fchunk;
  }

  f32x4 acc[4][4] = {};

  for (int ks = 0; ks < 16; ks++) {
    const int k0 = ks * BK;
    // global loads (independent of LDS)
    float4 q0 = *(const float4*)(qp + k0 + 0);
    float4 q1 = *(const float4*)(qp + k0 + 4);
    float4 q2 = *(const float4*)(qp + k0 + 8);
    float4 q3 = *(const float4*)(qp + k0 + 12);
    float4 w0 = *(const float4*)(wp + k0 + 0);
    float4 w1 = *(const float4*)(wp + k0 + 4);
    float4 w2 = *(const float4*)(wp + k0 + 8);
    float4 w3 = *(const float4*)(wp + k0 + 12);
    float4 c0 = *(const float4*)(cp + k0 + 0);
    float4 c1 = *(const float4*)(cp + k0 + 4);
    float4 c2 = *(const float4*)(cp + k0 + 8);
    float4 c3 = *(const float4*)(cp + k0 + 12);
    q0.x *= w0.x; q0.y *= w0.y; q0.z *= w0.z; q0.w *= w0.w;
    q1.x *= w1.x; q1.y *= w1.y; q1.z *= w1.z; q1.w *= w1.w;
    q2.x *= w2.x; q2.y *= w2.y; q2.z *= w2.z; q2.w *= w2.w;
    q3.x *= w3.x; q3.y *= w3.y; q3.z *= w3.z; q3.w *= w3.w;

    __syncthreads();  // previous iter's fragment reads complete
    uint4 h, l;
    pack8(q0, q1, h, l); Ahi[slotA0] = h; Alo[slotA0] = l;
    pack8(q2, q3, h, l); Ahi[slotA1] = h; Alo[slotA1] = l;
    pack8(c0, c1, h, l); Bhi[slotA0] = h; Blo[slotA0] = l;
    pack8(c2, c3, h, l); Bhi[slotA1] = h; Blo[slotA1] = l;
    __syncthreads();  // tiles visible

    short8 bh[4], bl[4];
#pragma unroll
    for (int ni = 0; ni < 4; ni++) {
      bh[ni] = bc8(Bhi[bslot[ni]]);
      bl[ni] = bc8(Blo[bslot[ni]]);
    }
#pragma unroll
    for (int mi = 0; mi < 4; mi++) {
      short8 ah = bc8(Ahi[aslot[mi]]);
      short8 al = bc8(Alo[aslot[mi]]);
#pragma unroll
      for (int ni = 0; ni < 4; ni++) {
        acc[mi][ni] = __builtin_amdgcn_mfma_f32_16x16x32_bf16(ah, bh[ni], acc[mi][ni], 0, 0, 0);
        acc[mi][ni] = __builtin_amdgcn_mfma_f32_16x16x32_bf16(al, bh[ni], acc[mi][ni], 0, 0, 0);
        acc[mi][ni] = __builtin_amdgcn_mfma_f32_16x16x32_bf16(ah, bl[ni], acc[mi][ni], 0, 0, 0);
      }
    }
  }

  // epilogue: C/D layout col=lane&15, row=(lane>>4)*4+reg
#pragma unroll
  for (int mi = 0; mi < 4; mi++) {
#pragma unroll
    for (int ni = 0; ni < 4; ni++) {
      const int j = wm + mi * 16 + q * 4;
      const int t = t0 + wn + ni * 16 + l15;
      float* dst = S + ((size_t)b * JJ + j) * TT + t;
      dst[0 * TT] = acc[mi][ni][0];
      dst[1 * TT] = acc[mi][ni][1];
      dst[2 * TT] = acc[mi][ni][2];
      dst[3 * TT] = acc[mi][ni][3];
    }
  }
}

// ---------------- Kernel B: per-(b,j) softmax stats over valid t -------------
// Single pass: whole 2048-row in registers (8 floats/thread), masked max+sum.
__global__ __launch_bounds__(256)
void softmax_stats_kernel(const float* __restrict__ S, const int* __restrict__ qlen,
                          const int* __restrict__ clen, float* __restrict__ m_out,
                          float* __restrict__ r_out) {
  const int j = blockIdx.x;
  const int b = blockIdx.y;
  if (j >= qlen[b]) return;
  const int cl = clen[b];
  const int tid = threadIdx.x;
  const float4* row = (const float4*)(S + ((size_t)b * JJ + j) * TT);

  float4 v0 = row[tid];
  float4 v1 = row[tid + 256];
  const int t0 = tid * 4;
  const int t1 = (tid + 256) * 4;
  const float NEG = -3.4e38f;

  float m = NEG;
  m = fmaxf(m, (t0 + 0 < cl) ? v0.x : NEG);
  m = fmaxf(m, (t0 + 1 < cl) ? v0.y : NEG);
  m = fmaxf(m, (t0 + 2 < cl) ? v0.z : NEG);
  m = fmaxf(m, (t0 + 3 < cl) ? v0.w : NEG);
  m = fmaxf(m, (t1 + 0 < cl) ? v1.x : NEG);
  m = fmaxf(m, (t1 + 1 < cl) ? v1.y : NEG);
  m = fmaxf(m, (t1 + 2 < cl) ? v1.z : NEG);
  m = fmaxf(m, (t1 + 3 < cl) ? v1.w : NEG);

  __shared__ float red[8];
#pragma unroll
  for (int off = 32; off > 0; off >>= 1) m = fmaxf(m, __shfl_down(m, off));
  if ((tid & 63) == 0) red[tid >> 6] = m;
  __syncthreads();
  m = fmaxf(fmaxf(red[0], red[1]), fmaxf(red[2], red[3]));

  float s = 0.f;
  s += (t0 + 0 < cl) ? __expf(v0.x - m) : 0.f;
  s += (t0 + 1 < cl) ? __expf(v0.y - m) : 0.f;
  s += (t0 + 2 < cl) ? __expf(v0.z - m) : 0.f;
  s += (t0 + 3 < cl) ? __expf(v0.w - m) : 0.f;
  s += (t1 + 0 < cl) ? __expf(v1.x - m) : 0.f;
  s += (t1 + 1 < cl) ? __expf(v1.y - m) : 0.f;
  s += (t1 + 2 < cl) ? __expf(v1.z - m) : 0.f;
  s += (t1 + 3 < cl) ? __expf(v1.w - m) : 0.f;
#pragma unroll
  for (int off = 32; off > 0; off >>= 1) s += __shfl_down(s, off);
  if ((tid & 63) == 0) red[4 + (tid >> 6)] = s;
  __syncthreads();
  s = red[4] + red[5] + red[6] + red[7];

  if (tid == 0) {
    m_out[(size_t)b * JJ + j] = m;
    r_out[(size_t)b * JJ + j] = 1.f / s;
  }
}

// ---------------- Kernel C: out[b,t] = sum_{j<qlen} exp(S-m)*r ---------------
__global__ __launch_bounds__(256)
void out_kernel(const float* __restrict__ S, const float* __restrict__ m_arr,
                const float* __restrict__ r_arr, const int* __restrict__ qlen,
                const int* __restrict__ clen, float* __restrict__ out) {
  const int b = blockIdx.y;
  const int t = blockIdx.x * 256 + threadIdx.x;
  const int ql = qlen[b];
  const int cl = clen[b];

  __shared__ float lm[JJ];
  __shared__ float lr[JJ];
  if (threadIdx.x < ql) {
    lm[threadIdx.x] = m_arr[(size_t)b * JJ + threadIdx.x];
    lr[threadIdx.x] = r_arr[(size_t)b * JJ + threadIdx.x];
  }
  __syncthreads();

  float acc = 0.f;
  if (t < cl) {
    const float* col = S + (size_t)b * JJ * TT + t;
#pragma unroll 4
    for (int j = 0; j < ql; j++) {
      acc += __expf(col[(size_t)j * TT] - lm[j]) * lr[j];
    }
  }
  out[(size_t)b * TT + t] = acc;
}

extern "C" void kernel_launch(void* const* d_in, const int* in_sizes, int n_in,
                              void* d_out, int out_size, void* d_ws, size_t ws_size,
                              hipStream_t stream) {
  const float* question = (const float*)d_in[0];  // (B,J,D)
  const float* context  = (const float*)d_in[1];  // (B,T,D)
  const int*   qlen     = (const int*)d_in[2];    // (B,)
  const int*   clen     = (const int*)d_in[3];    // (B,)
  const float* weight   = (const float*)d_in[4];  // (D,1)
  float* out = (float*)d_out;                     // (B,T,1) f32

  // Workspace: S (B*J*T f32 = 64 MB) + m (B*J) + r (B*J)
  float* S = (float*)d_ws;
  float* m_arr = S + (size_t)BB * JJ * TT;
  float* r_arr = m_arr + (size_t)BB * JJ;

  sim_gemm_mfma<<<dim3(TT / 128, BB), 256, 0, stream>>>(question, context, weight, S);
  softmax_stats_kernel<<<dim3(JJ, BB), 256, 0, stream>>>(S, qlen, clen, m_arr, r_arr);
  out_kernel<<<dim3(TT / 256, BB), 256, 0, stream>>>(S, m_arr, r_arr, qlen, clen, out);
}